// Round 2
// baseline (253.618 us; speedup 1.0000x reference)
//
#include <hip/hip_runtime.h>

#define T_STEPS 2000
#define BATCH   2048
#define TT      16      // pass-1 t-tile per wave
#define NCHUNK  125     // 2000 / 16

// DPP helper: ctrl is a compile-time immediate.
// quad_perm broadcast of quad-lane q: CTRL = q*0x55 (0x00,0x55,0xAA,0xFF)
// row_shl:1 = 0x101: dst[n] = src[n+1] within each 16-lane row (data moves to
// lower lanes; row-edge lanes get 0 via bound_ctrl). Direction anchors:
// wave_rol:1 (0x134) = dst[L]=src[L+1] (verified in passing round-0 kernel);
// row_shr:1 = dst[n]=src[n-1] (canonical DPP scan idiom). We need src[n+1] -> shl.
template<int CTRL>
__device__ __forceinline__ float dppf(float v) {
    int i = __builtin_bit_cast(int, v);
    return __builtin_bit_cast(float,
        __builtin_amdgcn_update_dpp(i, i, CTRL, 0xf, 0xf, true));
}

// ---------------------------------------------------------------------------
// Pass 1: X[t][c] = (sum_k a[k] * c[t-63+k][c] - b_act) / max_current
// Pure convolution of the inputs -> embarrassingly parallel.
// Written into `out` (used as scratch; pass 2 reads X[t] before writing f[t]).
// ---------------------------------------------------------------------------
__global__ __launch_bounds__(64) void conv_kernel(
    const float* __restrict__ currents, const float* __restrict__ a,
    const float* __restrict__ b_act, const float* __restrict__ max_current,
    float* __restrict__ X)
{
    int lane = threadIdx.x;
    int t0   = blockIdx.x * TT;          // 125 t-tiles
    int c    = blockIdx.y * 64 + lane;   // 32 c-tiles

    float inv = 1.0f / max_current[0];
    float cb  = -b_act[0] * inv;

    float cur[TT + 63];
#pragma unroll
    for (int rr = 0; rr < TT + 63; ++rr) {
        int r = t0 - 63 + rr;            // max r = t0+TT-1 <= 1999
        cur[rr] = (r >= 0) ? currents[(long)r * BATCH + c] : 0.0f;
    }
#pragma unroll
    for (int i = 0; i < TT; ++i) {
        float acc = 0.0f;
#pragma unroll
        for (int k = 0; k < 64; ++k)
            acc = fmaf(a[k], cur[i + k], acc);   // a[k]: scalar (s_load) operand
        X[(long)(t0 + i) * BATCH + c] = fmaf(acc, inv, cb);
    }
}

// ---------------------------------------------------------------------------
// Pass 2: serial feedback recurrence. Wave = 16 columns x 4 lanes/column.
// Lane L: column cc = L>>2, quad-slot q = L&3. Each lane holds 16 of the 64
// feedback-ring partial sums. Phase-renamed mapping: at phase phi, register
// ring[r] in quad-lane q holds ring position pi = 16q + ((r - phi) mod 16).
// Position 0 (the completed y_t) is ring[phi] at q=0. Per step:
//   u = ring[phi](q=0) + X_t  ->  f = relu(M*tanh(poly(u)))
//   cross-lane shift of ring[phi] only (row_shl:1: lane q <- lane q+1),
//   newborn slot (q=3) = 0, then ring[p] += tap[(p-1-phi)&15] * f for all p.
// tap(pi) = (1000/mc) * b_lag[63-pi]; conv+bias already folded into X.
// ---------------------------------------------------------------------------
__global__ __launch_bounds__(64) void rec_kernel(
    const float* X,                       // == out (scratch from pass 1)
    const float* __restrict__ b_lag, const float* __restrict__ poly_coeff,
    const float* __restrict__ max_current, const float* __restrict__ max_firing_rate,
    float* out)
{
    int lane = threadIdx.x;
    int q    = lane & 3;
    int cc   = lane >> 2;
    long col = (long)blockIdx.x * 16 + cc;

    float inv    = 1.0f / max_current[0];
    float gscale = 1000.0f * inv;
    float tap[16];
#pragma unroll
    for (int j = 0; j < 16; ++j)
        tap[j] = gscale * b_lag[63 - (16 * q + j)];

    // tanh(p) = 1 - 2/(exp2(K2*p)+1); K2 = 2*log2(e) folded into squared coeffs.
    const float K2 = 2.8853900817779268f;
    float c0 = poly_coeff[0], c1 = poly_coeff[1], c2 = poly_coeff[2], c3 = poly_coeff[3];
    float k0 = K2*c0*c0, k1 = K2*c1*c1, k2 = K2*c2*c2, k3 = K2*c3*c3;
    float M  = max_firing_rate[0];
    float m2 = -2.0f * M;

    bool e0 = (q == 0), e1 = (q == 1), e2 = (q == 2), q3 = (q == 3);

    float ring[16];
#pragma unroll
    for (int j = 0; j < 16; ++j) ring[j] = 0.0f;

    const float* xp = X + col;
    float*       op = out + col;

    // X chunk buffer: xa[g] lane(cc,q) = X[t0 + 4g + q][col]
    float xa0 = xp[(long)(0  + q) * BATCH];
    float xa1 = xp[(long)(4  + q) * BATCH];
    float xa2 = xp[(long)(8  + q) * BATCH];
    float xa3 = xp[(long)(12 + q) * BATCH];

    for (int ch = 0; ch < NCHUNK; ++ch) {
        long tn = (long)(ch + 1) * 16;
        float xb0 = 0.f, xb1 = 0.f, xb2 = 0.f, xb3 = 0.f;
        if (tn < T_STEPS) {              // prefetch next chunk (disjoint from stores)
            xb0 = xp[(tn + 0 ) * BATCH + (long)q * BATCH];
            xb1 = xp[(tn + 4 ) * BATCH + (long)q * BATCH];
            xb2 = xp[(tn + 8 ) * BATCH + (long)q * BATCH];
            xb3 = xp[(tn + 12) * BATCH + (long)q * BATCH];
        }
        float fv0 = 0.f, fv1 = 0.f, fv2 = 0.f, fv3 = 0.f;
#pragma unroll
        for (int phi = 0; phi < 16; ++phi) {
            float xsrc = (phi < 4) ? xa0 : (phi < 8) ? xa1 : (phi < 12) ? xa2 : xa3;
            float x_bc;
            // broadcast quad-lane (phi&3) -> whole quad (compile-time ctrl)
            if      ((phi & 3) == 0) x_bc = dppf<0x00>(xsrc);
            else if ((phi & 3) == 1) x_bc = dppf<0x55>(xsrc);
            else if ((phi & 3) == 2) x_bc = dppf<0xAA>(xsrc);
            else                     x_bc = dppf<0xFF>(xsrc);

            float u0 = ring[phi] + x_bc;       // valid at q==0 (pi=0 slot)
            float u  = dppf<0x00>(u0);         // broadcast to the quad
            float u2 = u * u;                  // Estrin, depth 2
            float a1 = fmaf(u, k1, k0);
            float a2 = fmaf(u, k3, k2);
            float p  = fmaf(u2, a2, a1);
            float e  = __builtin_amdgcn_exp2f(p);
            float r_ = __builtin_amdgcn_rcpf(e + 1.0f);
            float f  = fmaxf(fmaf(m2, r_, M), 0.0f);   // per-column f in its quad

            // stash f into the chunk's output regs (lane q == phi&3 keeps it)
            bool sel = ((phi & 3) == 0) ? e0 : ((phi & 3) == 1) ? e1
                     : ((phi & 3) == 2) ? e2 : q3;
            if      (phi < 4)  fv0 = sel ? f : fv0;
            else if (phi < 8)  fv1 = sel ? f : fv1;
            else if (phi < 12) fv2 = sel ? f : fv2;
            else               fv3 = sel ? f : fv3;

            // cross-lane ring shift: value at lane q must arrive at lane q-1,
            // i.e. dst[n] = src[n+1] -> row_shl:1 (0x101). Newborn slot (q=3) = 0.
            float sh = dppf<0x101>(ring[phi]);
            ring[phi] = q3 ? 0.0f : sh;

            // apply feedback taps: every position gets tap(pi)*f_t
#pragma unroll
            for (int p2 = 0; p2 < 16; ++p2)
                ring[p2] = fmaf(tap[(p2 - 1 - phi) & 15], f, ring[p2]);
        }
        long t0 = (long)ch * 16;
        op[(t0 + 0  + q) * BATCH] = fv0;
        op[(t0 + 4  + q) * BATCH] = fv1;
        op[(t0 + 8  + q) * BATCH] = fv2;
        op[(t0 + 12 + q) * BATCH] = fv3;
        xa0 = xb0; xa1 = xb1; xa2 = xb2; xa3 = xb3;
    }
}

extern "C" void kernel_launch(void* const* d_in, const int* in_sizes, int n_in,
                              void* d_out, int out_size, void* d_ws, size_t ws_size,
                              hipStream_t stream) {
    const float* currents   = (const float*)d_in[0];
    const float* a          = (const float*)d_in[1];
    const float* b_lag      = (const float*)d_in[2];
    const float* poly_coeff = (const float*)d_in[3];
    const float* b_act      = (const float*)d_in[4];
    const float* mc         = (const float*)d_in[5];
    const float* mfr        = (const float*)d_in[6];
    float* out = (float*)d_out;

    // Pass 1: conv + bias + 1/mc folded -> X, staged in `out`.
    conv_kernel<<<dim3(NCHUNK, BATCH / 64), 64, 0, stream>>>(currents, a, b_act, mc, out);
    // Pass 2: serial feedback recurrence, 16 columns/wave, 128 single-wave blocks.
    rec_kernel<<<BATCH / 16, 64, 0, stream>>>(out, b_lag, poly_coeff, mc, mfr, out);
}